// Round 3
// baseline (184.155 us; speedup 1.0000x reference)
//
#include <hip/hip_runtime.h>
#include <stdint.h>

#define G_   250
#define P_   200
#define EPG  3200
#define E_   800000
#define F_   128
#define R_   8
#define HROW 136   // f16 elems per row; 272 B stride, 16B-aligned rows
#define NKEY (R_ * P_)   // 1600 (rel,dst) buckets
#define BSTG (8 * 4 * 64 * 8)   // 16384 f16 = 32 KB per (l,r) B-fragment set

typedef _Float16 f16x8 __attribute__((ext_vector_type(8)));
typedef _Float16 f16x4 __attribute__((ext_vector_type(4)));
typedef float    f32x4 __attribute__((ext_vector_type(4)));
typedef float    f32x16 __attribute__((ext_vector_type(16)));

// ---------------- prepass: W -> B-fragment layout for mfma_f32_32x32x16_f16 ----------------
// flat = ((((l*9+r)*8 + kt)*4 + ntj)*64 + lane)*8 + j
// value = W[r][k = kt*16 + (lane>>5)*8 + j][n = ntj*32 + (lane&31)]  (r==8 -> root)
__global__ __launch_bounds__(256) void k_wstage(const float* __restrict__ W1, const float* __restrict__ root1,
                                                const float* __restrict__ W2, const float* __restrict__ root2,
                                                _Float16* __restrict__ wf) {
  int t = blockIdx.x * 256 + threadIdx.x;   // exactly 1152*256 = 2*9*8*4*64*8
  int j    = t & 7;
  int lane = (t >> 3) & 63;
  int ntj  = (t >> 9) & 3;
  int kt   = (t >> 11) & 7;
  int rl_  = t >> 14;          // 0..17
  int r = rl_ % 9, l = rl_ / 9;
  const float* Wl = (l == 0) ? W1 : W2;
  const float* rt = (l == 0) ? root1 : root2;
  int k = kt * 16 + (lane >> 5) * 8 + j;
  int n = ntj * 32 + (lane & 31);
  float v = (r < 8) ? Wl[(r * F_ + k) * F_ + n] : rt[k * F_ + n];
  wf[t] = (_Float16)v;
}

// ---------------- main: one workgroup = one graph; 16 waves (8 row-groups x 2 col-halves) ----
// Wave (rh,ch): rows [rh*25, rh*25+25), nt-cols {2ch, 2ch+1}. Column-partner waves duplicate
// the A-gather but split the MFMA N-dim -> acc = 32 VGPR/wave, 4 waves/SIMD TLP.
// B double-buffered: even r -> Bstage; odd r -> first 32 KB of the dead hbuf. 1 barrier/rel.
__global__ __launch_bounds__(1024, 4) void k_main(
    const float* __restrict__ x, const int* __restrict__ ei, const int* __restrict__ et,
    const _Float16* __restrict__ wf, const float* __restrict__ b1, const float* __restrict__ b2,
    const float* __restrict__ message, const float* __restrict__ embed,
    const float* __restrict__ cw, const float* __restrict__ cb,
    const float* __restrict__ mw, const float* __restrict__ mb,
    float* __restrict__ out) {
  __shared__ __attribute__((aligned(16))) _Float16 hbuf0[P_ * HROW];  // 54400 B
  __shared__ __attribute__((aligned(16))) _Float16 hbuf1[P_ * HROW];  // 54400 B
  __shared__ __attribute__((aligned(16))) _Float16 Bstage[BSTG];      // 32768 B
  __shared__ unsigned short csrS[EPG];                                // 6400 B
  __shared__ int offsS[NKEY + 1];                                     // 6404 B
  __shared__ float msgS[F_ + 1];                                      // 516 B
  __shared__ float scoreS[2 * P_];                                    // 1600 B -> 156488 B

  int g = blockIdx.x, tid = threadIdx.x;
  int lane = tid & 63, wave = tid >> 6;
  int m32 = lane & 31, kh = lane >> 5;

  // ---- setup scratch aliased inside hbuf1 (dead until first odd-r B commit) ----
  int*   Sint = (int*)hbuf1;
  int*   cnt  = Sint;                    // [1600]
  int*   cur  = Sint + 1600;             // [1600]
  int*   eRec = Sint + 3200;             // [3200]
  float* comb = (float*)(Sint + 6400);   // [256]
  float* red  = (float*)(Sint + 6656);   // [128]   => 27136 B < 54400 B

  // ---- issue (l=0, r=0) B-fragment loads immediately (land during phase 0) ----
  f16x8 st0[2];
  st0[0] = *((const f16x8*)(wf + tid * 8));
  st0[1] = *((const f16x8*)(wf + 8192 + tid * 8));

  // ---- phase 0: stage x -> hbuf0 (f16); zero cnt/cur; msg combined features ----
  for (int i = tid; i < P_ * 32; i += 1024) {
    int row = i >> 5, c4 = i & 31;
    const float4 v = ((const float4*)x)[(g * P_ + row) * 32 + c4];
    f16x4 pk = { (_Float16)v.x, (_Float16)v.y, (_Float16)v.z, (_Float16)v.w };
    *((f16x4*)&hbuf0[row * HROW + c4 * 4]) = pk;
  }
  for (int i = tid; i < NKEY; i += 1024) { cnt[i] = 0; cur[i] = 0; }
  if (tid < F_) {
    int tok = (int)message[g * 2];
    float cont = message[g * 2 + 1];
    comb[tid] = embed[tok * F_ + tid];
    float ce = cont * cw[tid] + cb[tid];
    comb[F_ + tid] = ce > 0.0f ? ce : 0.0f;
  }
  *((f16x8*)(Bstage + tid * 8)) = st0[0];
  *((f16x8*)(Bstage + 8192 + tid * 8)) = st0[1];
  __syncthreads();

  // ---- phase 1 (wave-specialized): edge ingest (14 waves) || message matmul (2 waves) ----
  int base = g * EPG, nbase = g * P_;
  if (wave == 12 || wave == 13) {
    int col = tid & 127;
    float acc = 0.0f;
#pragma unroll 16
    for (int k2 = 0; k2 < 256; k2++) acc += comb[k2] * mw[k2 * F_ + col];
    red[col] = acc;
  } else {
    int iw = (wave < 12) ? wave : (wave - 2);
    for (int e = iw * 64 + lane; e < EPG; e += 896) {
      int s = ei[base + e] - nbase;
      int d = ei[E_ + base + e] - nbase;
      int r = et[base + e];
      eRec[e] = s | (d << 8) | (r << 16);
      atomicAdd(&cnt[r * P_ + d], 1);
    }
  }
  __syncthreads();

  // ---- phase 2: wave0 = offset scan (shfl); wave1 = msg finalize ----
  if (wave == 0) {
    int4 vv[8];
    int osum = 0;
    if (lane < 50) {
      const int4* cp = (const int4*)(cnt + lane * 32);
#pragma unroll
      for (int i = 0; i < 8; i++) { vv[i] = cp[i]; osum += vv[i].x + vv[i].y + vv[i].z + vv[i].w; }
    }
    int incl = osum;
#pragma unroll
    for (int d = 1; d < 64; d <<= 1) {
      int t2 = __shfl_up(incl, d, 64);
      if (lane >= d) incl += t2;
    }
    int run = incl - osum;   // exclusive prefix
    if (lane < 50) {
#pragma unroll
      for (int i = 0; i < 8; i++) {
        offsS[lane * 32 + i * 4 + 0] = run; run += vv[i].x;
        offsS[lane * 32 + i * 4 + 1] = run; run += vv[i].y;
        offsS[lane * 32 + i * 4 + 2] = run; run += vv[i].z;
        offsS[lane * 32 + i * 4 + 3] = run; run += vv[i].w;
      }
    }
    if (lane == 0) offsS[NKEY] = EPG;
  } else if (wave == 1) {
    float m0 = mb[lane] + red[lane];
    float m1 = mb[lane + 64] + red[lane + 64];
    m0 = m0 > 0.0f ? m0 : 0.0f;
    m1 = m1 > 0.0f ? m1 : 0.0f;
    msgS[lane] = m0; msgS[lane + 64] = m1;
    float p = m0 * b2[lane] + m1 * b2[lane + 64];
#pragma unroll
    for (int d = 32; d > 0; d >>= 1) p += __shfl_xor(p, d, 64);
    if (lane == 0) msgS[F_] = p;
  }
  __syncthreads();

  // ---- phase 3: CSR scatter from LDS records ----
  for (int e = tid; e < EPG; e += 1024) {
    int rec = eRec[e];
    int s = rec & 255, d = (rec >> 8) & 255, r = rec >> 16;
    int key = r * P_ + d;
    int pos = atomicAdd(&cur[key], 1);
    csrS[offsS[key] + pos] = (unsigned short)s;
  }
  __syncthreads();   // hbuf0 + csr + offs + msg + Bstage(l0,r0) ready; hbuf1 scratch dead

  // ---- fused layers ----
  int rh = wave >> 1, ch = wave & 1;
  int jobBase = rh * 25;
  bool rowAct = (m32 < 25);
  int myD = jobBase + m32;
  int ck = kh * 8;
  int ntB = ch * 2;

  for (int l = 0; l < 2; l++) {
    const _Float16* Ap = (l == 0) ? hbuf0 : hbuf1;
    _Float16* balt = (l == 0) ? hbuf1 : hbuf0;   // odd-r B buffer aliases the dead hbuf
    f32x16 acc[2];
#pragma unroll
    for (int nt = 0; nt < 2; nt++)
#pragma unroll
      for (int i = 0; i < 16; i++) acc[nt][i] = 0.0f;
    const _Float16* wl = wf + l * (9 * BSTG);
    for (int r = 0; r < 9; r++) {
      // ---- issue next-set staging loads (r+1, or l=1's r=0 at the layer boundary) ----
      f16x8 st2[2];
      bool haveNext = (r < 8) || (l == 0);
      if (haveNext) {
        const _Float16* wnext = (r < 8) ? (wl + (r + 1) * BSTG) : (wf + 9 * BSTG);
        st2[0] = *((const f16x8*)(wnext + tid * 8));
        st2[1] = *((const f16x8*)(wnext + 8192 + tid * 8));
      }
      // ---- gather this lane's A row for relation r ----
      f16x8 a[8];
      if (r < 8) {
        int o = 0, n = 0;
        if (rowAct) { int key = r * P_ + myD; o = offsS[key]; n = offsS[key + 1] - o; }
        f16x8 z = {0, 0, 0, 0, 0, 0, 0, 0};
#pragma unroll
        for (int kt = 0; kt < 8; kt++) a[kt] = z;
        for (int t = 0; t < n; t++) {
          int s0 = (int)csrS[o + t];
          const _Float16* hp0 = &Ap[s0 * HROW + ck];
#pragma unroll
          for (int kt = 0; kt < 8; kt++) a[kt] += *((const f16x8*)(hp0 + kt * 16));
        }
        float nf = (n > 0) ? 1.0f / (float)n : 0.0f;
        _Float16 nh = (_Float16)nf;
#pragma unroll
        for (int kt = 0; kt < 8; kt++) a[kt] *= nh;
      } else {
        int rowA = jobBase + (rowAct ? m32 : 24);
        const _Float16* hp = &Ap[rowA * HROW + ck];
#pragma unroll
        for (int kt = 0; kt < 8; kt++) a[kt] = *((const f16x8*)(hp + kt * 16));
      }
      // ---- MFMA from the resident parity buffer (this wave's 2 nt columns only) ----
      const _Float16* bp = (r & 1) ? balt : Bstage;
#pragma unroll
      for (int kt = 0; kt < 8; kt++) {
#pragma unroll
        for (int ntl = 0; ntl < 2; ntl++) {
          f16x8 b = *((const f16x8*)&bp[((kt * 4 + ntB + ntl) * 64 + lane) * 8]);
          acc[ntl] = __builtin_amdgcn_mfma_f32_32x32x16_f16(a[kt], b, acc[ntl], 0, 0, 0);
        }
      }
      // ---- commit staged B to the other parity buffer; one barrier per relation ----
      if (r < 8) {
        _Float16* dst = ((r + 1) & 1) ? balt : Bstage;
        *((f16x8*)(dst + tid * 8)) = st2[0];
        *((f16x8*)(dst + 8192 + tid * 8)) = st2[1];
        __syncthreads();
      } else if (l == 0) {
        __syncthreads();   // all waves done with Bstage (r=8) and all l=0 gathers of hbuf0
        *((f16x8*)(Bstage + tid * 8)) = st2[0];
        *((f16x8*)(Bstage + 8192 + tid * 8)) = st2[1];   // (l=1, r=0); visible after epilogue barrier
      }
    }
    if (l == 0) {
      // h' = relu(acc + b1) -> hbuf1 (this wave's 2 nt columns)
#pragma unroll
      for (int ntl = 0; ntl < 2; ntl++) {
        int col = (ntB + ntl) * 32 + m32;
        float bias = b1[col];
#pragma unroll
        for (int reg = 0; reg < 16; reg++) {
          int row = (reg & 3) + 8 * (reg >> 2) + 4 * kh;
          if (row < 25) {
            float v = acc[ntl][reg] + bias;
            v = v > 0.0f ? v : 0.0f;
            hbuf1[(jobBase + row) * HROW + col] = (_Float16)v;
          }
        }
      }
      __syncthreads();   // h' + Bstage(l1,r0) complete before layer-2 gathers/MFMA
    } else {
      // partial score over this wave's 64 cols; combine halves via scoreS
      float mg0 = msgS[ntB * 32 + m32];
      float mg1 = msgS[(ntB + 1) * 32 + m32];
#pragma unroll
      for (int reg = 0; reg < 16; reg++) {
        int row = (reg & 3) + 8 * (reg >> 2) + 4 * kh;
        float p = acc[0][reg] * mg0 + acc[1][reg] * mg1;
        p += __shfl_xor(p, 16, 32);
        p += __shfl_xor(p, 8, 32);
        p += __shfl_xor(p, 4, 32);
        p += __shfl_xor(p, 2, 32);
        p += __shfl_xor(p, 1, 32);
        if (m32 == 0 && row < 25)
          scoreS[ch * P_ + jobBase + row] = p;
      }
      __syncthreads();
      if (tid < P_)
        out[g * P_ + tid] = scoreS[tid] + scoreS[P_ + tid] + msgS[F_];
    }
  }
}

extern "C" void kernel_launch(void* const* d_in, const int* in_sizes, int n_in,
                              void* d_out, int out_size, void* d_ws, size_t ws_size,
                              hipStream_t stream) {
  const float* message = (const float*)d_in[0];
  const float* x       = (const float*)d_in[1];
  const int*   ei      = (const int*)d_in[2];
  const int*   et      = (const int*)d_in[3];
  const float* W1      = (const float*)d_in[6];
  const float* root1   = (const float*)d_in[7];
  const float* b1      = (const float*)d_in[8];
  const float* W2      = (const float*)d_in[9];
  const float* root2   = (const float*)d_in[10];
  const float* b2      = (const float*)d_in[11];
  const float* embed   = (const float*)d_in[12];
  const float* cw      = (const float*)d_in[13];
  const float* cb      = (const float*)d_in[14];
  const float* mw      = (const float*)d_in[15];
  const float* mb      = (const float*)d_in[16];

  _Float16* wfrag = (_Float16*)d_ws;   // 589,824 B
  float*    out   = (float*)d_out;

  hipLaunchKernelGGL(k_wstage, dim3(1152), dim3(256), 0, stream, W1, root1, W2, root2, wfrag);
  hipLaunchKernelGGL(k_main, dim3(G_), dim3(1024), 0, stream, x, ei, et, wfrag, b1, b2,
                     message, embed, cw, cb, mw, mb, out);
}

// Round 4
// 180.607 us; speedup vs baseline: 1.0196x; 1.0196x over previous
//
#include <hip/hip_runtime.h>
#include <stdint.h>

#define G_   250
#define P_   200
#define EPG  3200
#define E_   800000
#define F_   128
#define R_   8
#define HROW 136   // f16 elems per row; 272 B stride, 16B-aligned rows
#define NKEY (R_ * P_)   // 1600 (rel,dst) buckets
#define BSTG (8 * 4 * 64 * 8)   // 16384 f16 = 32 KB per (l,r) B-fragment set

typedef _Float16 f16x8 __attribute__((ext_vector_type(8)));
typedef _Float16 f16x4 __attribute__((ext_vector_type(4)));
typedef float    f32x4 __attribute__((ext_vector_type(4)));
typedef float    f32x16 __attribute__((ext_vector_type(16)));

// ---------------- prepass: W -> B-fragment layout for mfma_f32_32x32x16_f16 ----------------
// flat = ((((l*9+r)*8 + kt)*4 + ntj)*64 + lane)*8 + j
// value = W[r][k = kt*16 + (lane>>5)*8 + j][n = ntj*32 + (lane&31)]  (r==8 -> root)
__global__ __launch_bounds__(256) void k_wstage(const float* __restrict__ W1, const float* __restrict__ root1,
                                                const float* __restrict__ W2, const float* __restrict__ root2,
                                                _Float16* __restrict__ wf) {
  int t = blockIdx.x * 256 + threadIdx.x;   // exactly 1152*256 = 2*9*8*4*64*8
  int j    = t & 7;
  int lane = (t >> 3) & 63;
  int ntj  = (t >> 9) & 3;
  int kt   = (t >> 11) & 7;
  int rl_  = t >> 14;          // 0..17
  int r = rl_ % 9, l = rl_ / 9;
  const float* Wl = (l == 0) ? W1 : W2;
  const float* rt = (l == 0) ? root1 : root2;
  int k = kt * 16 + (lane >> 5) * 8 + j;
  int n = ntj * 32 + (lane & 31);
  float v = (r < 8) ? Wl[(r * F_ + k) * F_ + n] : rt[k * F_ + n];
  wf[t] = (_Float16)v;
}

// ---------------- main: one workgroup = one graph; 8 waves x 25 rows; B direct from L1/L2 ----
// All 8 waves read the SAME 32 KB B-set per relation -> wave 0 misses to L2 (weights fully
// L2-resident), waves 1-7 hit L1. No Bstage, no commits, no r-loop barriers: waves drift
// freely; only sync points are after setup and at the layer boundary (h' visibility).
__global__ __launch_bounds__(512, 2) void k_main(
    const float* __restrict__ x, const int* __restrict__ ei, const int* __restrict__ et,
    const _Float16* __restrict__ wf, const float* __restrict__ b1, const float* __restrict__ b2,
    const float* __restrict__ message, const float* __restrict__ embed,
    const float* __restrict__ cw, const float* __restrict__ cb,
    const float* __restrict__ mw, const float* __restrict__ mb,
    float* __restrict__ out) {
  __shared__ __attribute__((aligned(16))) _Float16 hbuf0[P_ * HROW];  // 54400 B
  __shared__ __attribute__((aligned(16))) _Float16 hbuf1[P_ * HROW];  // 54400 B
  __shared__ unsigned short csrS[EPG];                                // 6400 B
  __shared__ int offsS[NKEY + 1];                                     // 6404 B
  __shared__ float msgS[F_ + 1];                                      // 516 B  -> 122120 B

  int g = blockIdx.x, tid = threadIdx.x;
  int lane = tid & 63, wave = tid >> 6;
  int m32 = lane & 31, kh = lane >> 5;

  // ---- setup scratch aliased inside hbuf1 (dead after phase 3) ----
  int*   Sint = (int*)hbuf1;
  int*   cnt  = Sint;                    // [1600]
  int*   cur  = Sint + 1600;             // [1600]
  int*   eRec = Sint + 3200;             // [3200]
  float* comb = (float*)(Sint + 6400);   // [256]
  float* red  = (float*)(Sint + 6656);   // [128]   => 27136 B < 54400 B

  // ---- phase 0: stage x -> hbuf0 (f16); zero cnt/cur; msg combined features ----
  for (int i = tid; i < P_ * 32; i += 512) {
    int row = i >> 5, c4 = i & 31;
    const float4 v = ((const float4*)x)[(g * P_ + row) * 32 + c4];
    f16x4 pk = { (_Float16)v.x, (_Float16)v.y, (_Float16)v.z, (_Float16)v.w };
    *((f16x4*)&hbuf0[row * HROW + c4 * 4]) = pk;
  }
  for (int i = tid; i < NKEY; i += 512) { cnt[i] = 0; cur[i] = 0; }
  if (tid < F_) {
    int tok = (int)message[g * 2];
    float cont = message[g * 2 + 1];
    comb[tid] = embed[tok * F_ + tid];
    float ce = cont * cw[tid] + cb[tid];
    comb[F_ + tid] = ce > 0.0f ? ce : 0.0f;
  }
  __syncthreads();

  // ---- phase 1 (wave-specialized): edge ingest || message matmul ----
  int base = g * EPG, nbase = g * P_;
  if (wave < 6) {
    for (int e = wave * 64 + lane; e < EPG; e += 384) {
      int s = ei[base + e] - nbase;
      int d = ei[E_ + base + e] - nbase;
      int r = et[base + e];
      eRec[e] = s | (d << 8) | (r << 16);
      atomicAdd(&cnt[r * P_ + d], 1);
    }
  } else {
    int col = tid & 127;
    float acc = 0.0f;
#pragma unroll 16
    for (int k2 = 0; k2 < 256; k2++) acc += comb[k2] * mw[k2 * F_ + col];
    red[col] = acc;
  }
  __syncthreads();

  // ---- phase 2: wave0 = offset scan (shfl); wave1 = msg finalize ----
  if (wave == 0) {
    int4 vv[8];
    int osum = 0;
    if (lane < 50) {
      const int4* cp = (const int4*)(cnt + lane * 32);
#pragma unroll
      for (int i = 0; i < 8; i++) { vv[i] = cp[i]; osum += vv[i].x + vv[i].y + vv[i].z + vv[i].w; }
    }
    int incl = osum;
#pragma unroll
    for (int d = 1; d < 64; d <<= 1) {
      int t2 = __shfl_up(incl, d, 64);
      if (lane >= d) incl += t2;
    }
    int run = incl - osum;   // exclusive prefix
    if (lane < 50) {
#pragma unroll
      for (int i = 0; i < 8; i++) {
        offsS[lane * 32 + i * 4 + 0] = run; run += vv[i].x;
        offsS[lane * 32 + i * 4 + 1] = run; run += vv[i].y;
        offsS[lane * 32 + i * 4 + 2] = run; run += vv[i].z;
        offsS[lane * 32 + i * 4 + 3] = run; run += vv[i].w;
      }
    }
    if (lane == 0) offsS[NKEY] = EPG;
  } else if (wave == 1) {
    float m0 = mb[lane] + red[lane];
    float m1 = mb[lane + 64] + red[lane + 64];
    m0 = m0 > 0.0f ? m0 : 0.0f;
    m1 = m1 > 0.0f ? m1 : 0.0f;
    msgS[lane] = m0; msgS[lane + 64] = m1;
    float p = m0 * b2[lane] + m1 * b2[lane + 64];
#pragma unroll
    for (int d = 32; d > 0; d >>= 1) p += __shfl_xor(p, d, 64);
    if (lane == 0) msgS[F_] = p;
  }
  __syncthreads();

  // ---- phase 3: CSR scatter from LDS records ----
  for (int e = tid; e < EPG; e += 512) {
    int rec = eRec[e];
    int s = rec & 255, d = (rec >> 8) & 255, r = rec >> 16;
    int key = r * P_ + d;
    int pos = atomicAdd(&cur[key], 1);
    csrS[offsS[key] + pos] = (unsigned short)s;
  }
  __syncthreads();   // hbuf0 + csr + offs + msg ready; hbuf1 scratch dead

  // ---- fused layers: wave w owns rows [w*25, w*25+25); no intra-layer barriers ----
  int jobBase = wave * 25;
  bool rowAct = (m32 < 25);
  int myD = jobBase + m32;
  int ck = kh * 8;

  for (int l = 0; l < 2; l++) {
    const _Float16* Ap = (l == 0) ? hbuf0 : hbuf1;
    f32x16 acc[4];
#pragma unroll
    for (int nt = 0; nt < 4; nt++)
#pragma unroll
      for (int i = 0; i < 16; i++) acc[nt][i] = 0.0f;
    const _Float16* wl = wf + l * (9 * BSTG);
    for (int r = 0; r < 9; r++) {
      const _Float16* wr = wl + r * BSTG;
      // ---- issue B half-1 (kt 0..3): L2/L1 latency hides under the gather ----
      f16x8 bA[4][4];
#pragma unroll
      for (int kt = 0; kt < 4; kt++)
#pragma unroll
        for (int nt = 0; nt < 4; nt++)
          bA[kt][nt] = *((const f16x8*)(wr + ((kt * 4 + nt) * 64 + lane) * 8));
      // ---- gather this lane's A row for relation r (unroll-2) ----
      f16x8 a[8];
      if (r < 8) {
        int o = 0, n = 0;
        if (rowAct) { int key = r * P_ + myD; o = offsS[key]; n = offsS[key + 1] - o; }
        f16x8 z = {0, 0, 0, 0, 0, 0, 0, 0};
#pragma unroll
        for (int kt = 0; kt < 8; kt++) a[kt] = z;
        int t = 0;
        for (; t + 2 <= n; t += 2) {
          int s0 = (int)csrS[o + t];
          int s1 = (int)csrS[o + t + 1];
          const _Float16* hp0 = &Ap[s0 * HROW + ck];
          const _Float16* hp1 = &Ap[s1 * HROW + ck];
          f16x8 u0[8], u1[8];
#pragma unroll
          for (int kt = 0; kt < 8; kt++) u0[kt] = *((const f16x8*)(hp0 + kt * 16));
#pragma unroll
          for (int kt = 0; kt < 8; kt++) u1[kt] = *((const f16x8*)(hp1 + kt * 16));
#pragma unroll
          for (int kt = 0; kt < 8; kt++) a[kt] += u0[kt] + u1[kt];
        }
        if (t < n) {
          int s0 = (int)csrS[o + t];
          const _Float16* hp0 = &Ap[s0 * HROW + ck];
#pragma unroll
          for (int kt = 0; kt < 8; kt++) a[kt] += *((const f16x8*)(hp0 + kt * 16));
        }
        float nf = (n > 0) ? 1.0f / (float)n : 0.0f;
        _Float16 nh = (_Float16)nf;
#pragma unroll
        for (int kt = 0; kt < 8; kt++) a[kt] *= nh;
      } else {
        int rowA = jobBase + (rowAct ? m32 : 24);
        const _Float16* hp = &Ap[rowA * HROW + ck];
#pragma unroll
        for (int kt = 0; kt < 8; kt++) a[kt] = *((const f16x8*)(hp + kt * 16));
      }
      // ---- issue B half-2 (kt 4..7): latency hides under half-1's 16 MFMAs ----
      f16x8 bB[4][4];
#pragma unroll
      for (int kt = 0; kt < 4; kt++)
#pragma unroll
        for (int nt = 0; nt < 4; nt++)
          bB[kt][nt] = *((const f16x8*)(wr + (((kt + 4) * 4 + nt) * 64 + lane) * 8));
      // ---- MFMA ----
#pragma unroll
      for (int kt = 0; kt < 4; kt++)
#pragma unroll
        for (int nt = 0; nt < 4; nt++)
          acc[nt] = __builtin_amdgcn_mfma_f32_32x32x16_f16(a[kt], bA[kt][nt], acc[nt], 0, 0, 0);
#pragma unroll
      for (int kt = 0; kt < 4; kt++)
#pragma unroll
        for (int nt = 0; nt < 4; nt++)
          acc[nt] = __builtin_amdgcn_mfma_f32_32x32x16_f16(a[kt + 4], bB[kt][nt], acc[nt], 0, 0, 0);
    }
    if (l == 0) {
      // h' = relu(acc + b1) -> hbuf1; C layout: col=lane&31, row=(reg&3)+8*(reg>>2)+4*kh
#pragma unroll
      for (int nt = 0; nt < 4; nt++) {
        int col = nt * 32 + m32;
        float bias = b1[col];
#pragma unroll
        for (int reg = 0; reg < 16; reg++) {
          int row = (reg & 3) + 8 * (reg >> 2) + 4 * kh;
          if (row < 25) {
            float v = acc[nt][reg] + bias;
            v = v > 0.0f ? v : 0.0f;
            hbuf1[(jobBase + row) * HROW + col] = (_Float16)v;
          }
        }
      }
      __syncthreads();   // h' complete before layer-2 gathers
    } else {
      // score = dot(node_emb, msg) + dot(b2, msg)
      float db2 = msgS[F_];
#pragma unroll
      for (int reg = 0; reg < 16; reg++) {
        int row = (reg & 3) + 8 * (reg >> 2) + 4 * kh;
        float p = 0.0f;
#pragma unroll
        for (int nt = 0; nt < 4; nt++)
          p += acc[nt][reg] * msgS[nt * 32 + m32];
        p += __shfl_xor(p, 16, 32);
        p += __shfl_xor(p, 8, 32);
        p += __shfl_xor(p, 4, 32);
        p += __shfl_xor(p, 2, 32);
        p += __shfl_xor(p, 1, 32);
        if (m32 == 0 && row < 25)
          out[g * P_ + jobBase + row] = p + db2;
      }
    }
  }
}

extern "C" void kernel_launch(void* const* d_in, const int* in_sizes, int n_in,
                              void* d_out, int out_size, void* d_ws, size_t ws_size,
                              hipStream_t stream) {
  const float* message = (const float*)d_in[0];
  const float* x       = (const float*)d_in[1];
  const int*   ei      = (const int*)d_in[2];
  const int*   et      = (const int*)d_in[3];
  const float* W1      = (const float*)d_in[6];
  const float* root1   = (const float*)d_in[7];
  const float* b1      = (const float*)d_in[8];
  const float* W2      = (const float*)d_in[9];
  const float* root2   = (const float*)d_in[10];
  const float* b2      = (const float*)d_in[11];
  const float* embed   = (const float*)d_in[12];
  const float* cw      = (const float*)d_in[13];
  const float* cb      = (const float*)d_in[14];
  const float* mw      = (const float*)d_in[15];
  const float* mb      = (const float*)d_in[16];

  _Float16* wfrag = (_Float16*)d_ws;   // 589,824 B
  float*    out   = (float*)d_out;

  hipLaunchKernelGGL(k_wstage, dim3(1152), dim3(256), 0, stream, W1, root1, W2, root2, wfrag);
  hipLaunchKernelGGL(k_main, dim3(G_), dim3(512), 0, stream, x, ei, et, wfrag, b1, b2,
                     message, embed, cw, cb, mw, mb, out);
}

// Round 5
// 172.899 us; speedup vs baseline: 1.0651x; 1.0446x over previous
//
#include <hip/hip_runtime.h>
#include <stdint.h>

#define G_   250
#define P_   200
#define EPG  3200
#define E_   800000
#define F_   128
#define R_   8
#define HROW 136   // f16 elems per row; 272 B stride, 16B-aligned rows
#define NKEY (R_ * P_)   // 1600 (rel,dst) buckets
#define BSTG (8 * 4 * 64 * 8)   // 16384 f16 = 32 KB per (l,r) B-fragment set
#define GRP  2048               // f16 per B-group (4 frags x 64 lanes x 8)
#define NGRP 144                // 2 layers x 9 rels x 8 kt-groups

typedef _Float16 f16x8 __attribute__((ext_vector_type(8)));
typedef _Float16 f16x4 __attribute__((ext_vector_type(4)));
typedef float    f32x4 __attribute__((ext_vector_type(4)));
typedef float    f32x16 __attribute__((ext_vector_type(16)));

// ---------------- prepass: W -> B-fragment layout for mfma_f32_32x32x16_f16 ----------------
// flat = ((((l*9+r)*8 + kt)*4 + ntj)*64 + lane)*8 + j   (group-major: group g at wf + g*2048)
// value = W[r][k = kt*16 + (lane>>5)*8 + j][n = ntj*32 + (lane&31)]  (r==8 -> root)
__global__ __launch_bounds__(256) void k_wstage(const float* __restrict__ W1, const float* __restrict__ root1,
                                                const float* __restrict__ W2, const float* __restrict__ root2,
                                                _Float16* __restrict__ wf) {
  int t = blockIdx.x * 256 + threadIdx.x;   // exactly 1152*256 = 2*9*8*4*64*8
  int j    = t & 7;
  int lane = (t >> 3) & 63;
  int ntj  = (t >> 9) & 3;
  int kt   = (t >> 11) & 7;
  int rl_  = t >> 14;          // 0..17
  int r = rl_ % 9, l = rl_ / 9;
  const float* Wl = (l == 0) ? W1 : W2;
  const float* rt = (l == 0) ? root1 : root2;
  int k = kt * 16 + (lane >> 5) * 8 + j;
  int n = ntj * 32 + (lane & 31);
  float v = (r < 8) ? Wl[(r * F_ + k) * F_ + n] : rt[k * F_ + n];
  wf[t] = (_Float16)v;
}

// ---------------- main: one workgroup = one graph; 8 waves x 25 rows ----------------
// B streams from global (L1-shared across the 8 waves) through a 4-slot register ring at
// kt-group granularity (prefetch distance 2). No r-loop barriers: waves drift freely so one
// wave's gather (LDS pipe) anti-phases another's MFMA (matrix pipe). Ring index (kt+c)&3 is
// compile-time static because groups/rel = 8 and groups/layer = 72 are both = 0 mod 4.
__global__ __launch_bounds__(512, 1) void k_main(
    const float* __restrict__ x, const int* __restrict__ ei, const int* __restrict__ et,
    const _Float16* __restrict__ wf, const float* __restrict__ b1, const float* __restrict__ b2,
    const float* __restrict__ message, const float* __restrict__ embed,
    const float* __restrict__ cw, const float* __restrict__ cb,
    const float* __restrict__ mw, const float* __restrict__ mb,
    float* __restrict__ out) {
  __shared__ __attribute__((aligned(16))) _Float16 hbuf0[P_ * HROW];  // 54400 B
  __shared__ __attribute__((aligned(16))) _Float16 hbuf1[P_ * HROW];  // 54400 B
  __shared__ unsigned short csrS[EPG];                                // 6400 B
  __shared__ int offsS[NKEY + 1];                                     // 6404 B
  __shared__ float msgS[F_ + 1];                                      // 516 B  -> 122120 B

  int g = blockIdx.x, tid = threadIdx.x;
  int lane = tid & 63, wave = tid >> 6;
  int m32 = lane & 31, kh = lane >> 5;

  // ---- setup scratch aliased inside hbuf1 (dead after phase 3) ----
  int*   Sint = (int*)hbuf1;
  int*   cnt  = Sint;                    // [1600]
  int*   cur  = Sint + 1600;             // [1600]
  int*   eRec = Sint + 3200;             // [3200]
  float* comb = (float*)(Sint + 6400);   // [256]
  float* red  = (float*)(Sint + 6656);   // [128]   => 27136 B < 54400 B

  // ---- B-group register ring: issue groups 0,1 immediately (L2-cold latency hides
  //      under the entire setup) ----
  f16x8 bb[4][4];
  const _Float16* pf = wf;
  const _Float16* const pfEnd = wf + NGRP * GRP;
#pragma unroll
  for (int nt = 0; nt < 4; nt++) bb[0][nt] = *((const f16x8*)(pf + (nt * 64 + lane) * 8));
  pf += GRP;
#pragma unroll
  for (int nt = 0; nt < 4; nt++) bb[1][nt] = *((const f16x8*)(pf + (nt * 64 + lane) * 8));
  pf += GRP;

  // ---- phase 0: stage x -> hbuf0 (f16); zero cnt/cur; msg combined features ----
  for (int i = tid; i < P_ * 32; i += 512) {
    int row = i >> 5, c4 = i & 31;
    const float4 v = ((const float4*)x)[(g * P_ + row) * 32 + c4];
    f16x4 pk = { (_Float16)v.x, (_Float16)v.y, (_Float16)v.z, (_Float16)v.w };
    *((f16x4*)&hbuf0[row * HROW + c4 * 4]) = pk;
  }
  for (int i = tid; i < NKEY; i += 512) { cnt[i] = 0; cur[i] = 0; }
  if (tid < F_) {
    int tok = (int)message[g * 2];
    float cont = message[g * 2 + 1];
    comb[tid] = embed[tok * F_ + tid];
    float ce = cont * cw[tid] + cb[tid];
    comb[F_ + tid] = ce > 0.0f ? ce : 0.0f;
  }
  __syncthreads();

  // ---- phase 1 (wave-specialized): edge ingest || message matmul ----
  int base = g * EPG, nbase = g * P_;
  if (wave < 6) {
    for (int e = wave * 64 + lane; e < EPG; e += 384) {
      int s = ei[base + e] - nbase;
      int d = ei[E_ + base + e] - nbase;
      int r = et[base + e];
      eRec[e] = s | (d << 8) | (r << 16);
      atomicAdd(&cnt[r * P_ + d], 1);
    }
  } else {
    int col = tid & 127;
    float acc = 0.0f;
#pragma unroll 16
    for (int k2 = 0; k2 < 256; k2++) acc += comb[k2] * mw[k2 * F_ + col];
    red[col] = acc;
  }
  __syncthreads();

  // ---- phase 2: wave0 = offset scan (shfl); wave1 = msg finalize ----
  if (wave == 0) {
    int4 vv[8];
    int osum = 0;
    if (lane < 50) {
      const int4* cp = (const int4*)(cnt + lane * 32);
#pragma unroll
      for (int i = 0; i < 8; i++) { vv[i] = cp[i]; osum += vv[i].x + vv[i].y + vv[i].z + vv[i].w; }
    }
    int incl = osum;
#pragma unroll
    for (int d = 1; d < 64; d <<= 1) {
      int t2 = __shfl_up(incl, d, 64);
      if (lane >= d) incl += t2;
    }
    int run = incl - osum;   // exclusive prefix
    if (lane < 50) {
#pragma unroll
      for (int i = 0; i < 8; i++) {
        offsS[lane * 32 + i * 4 + 0] = run; run += vv[i].x;
        offsS[lane * 32 + i * 4 + 1] = run; run += vv[i].y;
        offsS[lane * 32 + i * 4 + 2] = run; run += vv[i].z;
        offsS[lane * 32 + i * 4 + 3] = run; run += vv[i].w;
      }
    }
    if (lane == 0) offsS[NKEY] = EPG;
  } else if (wave == 1) {
    float m0 = mb[lane] + red[lane];
    float m1 = mb[lane + 64] + red[lane + 64];
    m0 = m0 > 0.0f ? m0 : 0.0f;
    m1 = m1 > 0.0f ? m1 : 0.0f;
    msgS[lane] = m0; msgS[lane + 64] = m1;
    float p = m0 * b2[lane] + m1 * b2[lane + 64];
#pragma unroll
    for (int d = 32; d > 0; d >>= 1) p += __shfl_xor(p, d, 64);
    if (lane == 0) msgS[F_] = p;
  }
  __syncthreads();

  // ---- phase 3: CSR scatter from LDS records ----
  for (int e = tid; e < EPG; e += 512) {
    int rec = eRec[e];
    int s = rec & 255, d = (rec >> 8) & 255, r = rec >> 16;
    int key = r * P_ + d;
    int pos = atomicAdd(&cur[key], 1);
    csrS[offsS[key] + pos] = (unsigned short)s;
  }
  __syncthreads();   // hbuf0 + csr + offs + msg ready; hbuf1 scratch dead

  // ---- fused layers: wave w owns rows [w*25, w*25+25); no intra-layer barriers ----
  int jobBase = wave * 25;
  bool rowAct = (m32 < 25);
  int myD = jobBase + m32;
  int ck = kh * 8;

  for (int l = 0; l < 2; l++) {
    const _Float16* Ap = (l == 0) ? hbuf0 : hbuf1;
    f32x16 acc[4];
#pragma unroll
    for (int nt = 0; nt < 4; nt++)
#pragma unroll
      for (int i = 0; i < 16; i++) acc[nt][i] = 0.0f;
    for (int r = 0; r < 9; r++) {
      // ---- gather this lane's A row for relation r ----
      f16x8 a[8];
      if (r < 8) {
        int o = 0, n = 0;
        if (rowAct) { int key = r * P_ + myD; o = offsS[key]; n = offsS[key + 1] - o; }
        f16x8 z = {0, 0, 0, 0, 0, 0, 0, 0};
#pragma unroll
        for (int kt = 0; kt < 8; kt++) a[kt] = z;
        int t = 0;
        for (; t + 2 <= n; t += 2) {
          int s0 = (int)csrS[o + t];
          int s1 = (int)csrS[o + t + 1];
          const _Float16* hp0 = &Ap[s0 * HROW + ck];
          const _Float16* hp1 = &Ap[s1 * HROW + ck];
#pragma unroll
          for (int kt = 0; kt < 8; kt++) {
            f16x8 v0 = *((const f16x8*)(hp0 + kt * 16));
            f16x8 v1 = *((const f16x8*)(hp1 + kt * 16));
            a[kt] += v0;
            a[kt] += v1;
          }
        }
        if (t < n) {
          int s0 = (int)csrS[o + t];
          const _Float16* hp0 = &Ap[s0 * HROW + ck];
#pragma unroll
          for (int kt = 0; kt < 8; kt++) a[kt] += *((const f16x8*)(hp0 + kt * 16));
        }
        float nf = (n > 0) ? 1.0f / (float)n : 0.0f;
        _Float16 nh = (_Float16)nf;
#pragma unroll
        for (int kt = 0; kt < 8; kt++) a[kt] *= nh;
      } else {
        int rowA = jobBase + (rowAct ? m32 : 24);
        const _Float16* hp = &Ap[rowA * HROW + ck];
#pragma unroll
        for (int kt = 0; kt < 8; kt++) a[kt] = *((const f16x8*)(hp + kt * 16));
      }
      // ---- kt-group loop: issue group kt+2 into ring slot (kt+2)&3, MFMA group kt ----
#pragma unroll
      for (int kt = 0; kt < 8; kt++) {
        if (pf != pfEnd) {
#pragma unroll
          for (int nt = 0; nt < 4; nt++)
            bb[(kt + 2) & 3][nt] = *((const f16x8*)(pf + (nt * 64 + lane) * 8));
          pf += GRP;
        }
#pragma unroll
        for (int nt = 0; nt < 4; nt++)
          acc[nt] = __builtin_amdgcn_mfma_f32_32x32x16_f16(a[kt], bb[kt & 3][nt], acc[nt], 0, 0, 0);
      }
    }
    if (l == 0) {
      // h' = relu(acc + b1) -> hbuf1; C layout: col=lane&31, row=(reg&3)+8*(reg>>2)+4*kh
#pragma unroll
      for (int nt = 0; nt < 4; nt++) {
        int col = nt * 32 + m32;
        float bias = b1[col];
#pragma unroll
        for (int reg = 0; reg < 16; reg++) {
          int row = (reg & 3) + 8 * (reg >> 2) + 4 * kh;
          if (row < 25) {
            float v = acc[nt][reg] + bias;
            v = v > 0.0f ? v : 0.0f;
            hbuf1[(jobBase + row) * HROW + col] = (_Float16)v;
          }
        }
      }
      __syncthreads();   // h' complete before layer-2 gathers
    } else {
      // score = dot(node_emb, msg) + dot(b2, msg)
      float db2 = msgS[F_];
#pragma unroll
      for (int reg = 0; reg < 16; reg++) {
        int row = (reg & 3) + 8 * (reg >> 2) + 4 * kh;
        float p = 0.0f;
#pragma unroll
        for (int nt = 0; nt < 4; nt++)
          p += acc[nt][reg] * msgS[nt * 32 + m32];
        p += __shfl_xor(p, 16, 32);
        p += __shfl_xor(p, 8, 32);
        p += __shfl_xor(p, 4, 32);
        p += __shfl_xor(p, 2, 32);
        p += __shfl_xor(p, 1, 32);
        if (m32 == 0 && row < 25)
          out[g * P_ + jobBase + row] = p + db2;
      }
    }
  }
}

extern "C" void kernel_launch(void* const* d_in, const int* in_sizes, int n_in,
                              void* d_out, int out_size, void* d_ws, size_t ws_size,
                              hipStream_t stream) {
  const float* message = (const float*)d_in[0];
  const float* x       = (const float*)d_in[1];
  const int*   ei      = (const int*)d_in[2];
  const int*   et      = (const int*)d_in[3];
  const float* W1      = (const float*)d_in[6];
  const float* root1   = (const float*)d_in[7];
  const float* b1      = (const float*)d_in[8];
  const float* W2      = (const float*)d_in[9];
  const float* root2   = (const float*)d_in[10];
  const float* b2      = (const float*)d_in[11];
  const float* embed   = (const float*)d_in[12];
  const float* cw      = (const float*)d_in[13];
  const float* cb      = (const float*)d_in[14];
  const float* mw      = (const float*)d_in[15];
  const float* mb      = (const float*)d_in[16];

  _Float16* wfrag = (_Float16*)d_ws;   // 589,824 B
  float*    out   = (float*)d_out;

  hipLaunchKernelGGL(k_wstage, dim3(1152), dim3(256), 0, stream, W1, root1, W2, root2, wfrag);
  hipLaunchKernelGGL(k_main, dim3(G_), dim3(512), 0, stream, x, ei, et, wfrag, b1, b2,
                     message, embed, cw, cb, mw, mb, out);
}

// Round 6
// 169.219 us; speedup vs baseline: 1.0883x; 1.0217x over previous
//
#include <hip/hip_runtime.h>
#include <stdint.h>

#define G_   250
#define P_   200
#define EPG  3200
#define E_   800000
#define F_   128
#define R_   8
#define HROW 136   // f16 elems per row; 272 B stride, 16B-aligned rows
#define NKEY (R_ * P_)   // 1600 (rel,dst) buckets
#define BSTG (8 * 4 * 64 * 8)   // 16384 f16 = 32 KB per (l,r) B-fragment set

typedef _Float16 f16x8 __attribute__((ext_vector_type(8)));
typedef _Float16 f16x4 __attribute__((ext_vector_type(4)));
typedef float    f32x4 __attribute__((ext_vector_type(4)));
typedef float    f32x16 __attribute__((ext_vector_type(16)));

// ---------------- prepass: W -> B-fragment layout for mfma_f32_32x32x16_f16 ----------------
// flat = ((((l*9+r)*8 + kt)*4 + ntj)*64 + lane)*8 + j
// value = W[r][k = kt*16 + (lane>>5)*8 + j][n = ntj*32 + (lane&31)]  (r==8 -> root)
__global__ __launch_bounds__(256) void k_wstage(const float* __restrict__ W1, const float* __restrict__ root1,
                                                const float* __restrict__ W2, const float* __restrict__ root2,
                                                _Float16* __restrict__ wf) {
  int t = blockIdx.x * 256 + threadIdx.x;   // exactly 1152*256 = 2*9*8*4*64*8
  int j    = t & 7;
  int lane = (t >> 3) & 63;
  int ntj  = (t >> 9) & 3;
  int kt   = (t >> 11) & 7;
  int rl_  = t >> 14;          // 0..17
  int r = rl_ % 9, l = rl_ / 9;
  const float* Wl = (l == 0) ? W1 : W2;
  const float* rt = (l == 0) ? root1 : root2;
  int k = kt * 16 + (lane >> 5) * 8 + j;
  int n = ntj * 32 + (lane & 31);
  float v = (r < 8) ? Wl[(r * F_ + k) * F_ + n] : rt[k * F_ + n];
  wf[t] = (_Float16)v;
}

// ---- gather+mean one relation's A-fragments for one dst row into a named register set ----
__device__ __forceinline__ void gather_rel(f16x8 (&a)[8], const _Float16* __restrict__ Ap,
                                           const unsigned short* __restrict__ csr,
                                           const int* __restrict__ offs,
                                           int key, bool rowAct, int ck) {
  int o = 0, n = 0;
  if (rowAct) { o = offs[key]; n = offs[key + 1] - o; }
  f16x8 z = {0, 0, 0, 0, 0, 0, 0, 0};
#pragma unroll
  for (int kt = 0; kt < 8; kt++) a[kt] = z;
  int t = 0;
  for (; t + 2 <= n; t += 2) {
    int s0 = (int)csr[o + t];
    int s1 = (int)csr[o + t + 1];
    const _Float16* hp0 = &Ap[s0 * HROW + ck];
    const _Float16* hp1 = &Ap[s1 * HROW + ck];
    f16x8 u0[8], u1[8];
#pragma unroll
    for (int kt = 0; kt < 8; kt++) u0[kt] = *((const f16x8*)(hp0 + kt * 16));
#pragma unroll
    for (int kt = 0; kt < 8; kt++) u1[kt] = *((const f16x8*)(hp1 + kt * 16));
#pragma unroll
    for (int kt = 0; kt < 8; kt++) a[kt] += u0[kt] + u1[kt];
  }
  if (t < n) {
    int s0 = (int)csr[o + t];
    const _Float16* hp0 = &Ap[s0 * HROW + ck];
#pragma unroll
    for (int kt = 0; kt < 8; kt++) a[kt] += *((const f16x8*)(hp0 + kt * 16));
  }
  float nf = (n > 0) ? 1.0f / (float)n : 0.0f;
  _Float16 nh = (_Float16)nf;
#pragma unroll
  for (int kt = 0; kt < 8; kt++) a[kt] *= nh;
}

__device__ __forceinline__ void gather_root(f16x8 (&a)[8], const _Float16* __restrict__ Ap,
                                            int rowA, int ck) {
  const _Float16* hp = &Ap[rowA * HROW + ck];
#pragma unroll
  for (int kt = 0; kt < 8; kt++) a[kt] = *((const f16x8*)(hp + kt * 16));
}

// ---- one relation's 32 MFMAs; B frags chunk-read from the LDS parity buffer ----
__device__ __forceinline__ void mfma_rel(f32x16 (&acc)[4], const f16x8 (&a)[8],
                                         const _Float16* __restrict__ bp, int lane) {
  __builtin_amdgcn_s_setprio(1);
#pragma unroll
  for (int kt = 0; kt < 8; kt++) {
#pragma unroll
    for (int nt = 0; nt < 4; nt++) {
      f16x8 b = *((const f16x8*)&bp[((kt * 4 + nt) * 64 + lane) * 8]);
      acc[nt] = __builtin_amdgcn_mfma_f32_32x32x16_f16(a[kt], b, acc[nt], 0, 0, 0);
    }
  }
  __builtin_amdgcn_s_setprio(0);
}

// ---------------- main: one workgroup = one graph; 8 waves x 25 rows ----------------
// Software-pipelined r-loop: MFMA(r) consumes the a-set gathered LAST iteration while
// gather(r+1) fills the other named set -> MFMA has no dependency on this iteration's
// gather, so the scheduler can interleave gather ds_reads into the MFMA shadow.
// B double-buffered through LDS: even r -> Bstage, odd r -> dead-hbuf alias. 2 barriers/pair.
__global__ __launch_bounds__(512, 1) void k_main(
    const float* __restrict__ x, const int* __restrict__ ei, const int* __restrict__ et,
    const _Float16* __restrict__ wf, const float* __restrict__ b1, const float* __restrict__ b2,
    const float* __restrict__ message, const float* __restrict__ embed,
    const float* __restrict__ cw, const float* __restrict__ cb,
    const float* __restrict__ mw, const float* __restrict__ mb,
    float* __restrict__ out) {
  __shared__ __attribute__((aligned(16))) _Float16 hbuf0[P_ * HROW];  // 54400 B
  __shared__ __attribute__((aligned(16))) _Float16 hbuf1[P_ * HROW];  // 54400 B
  __shared__ __attribute__((aligned(16))) _Float16 Bstage[BSTG];      // 32768 B
  __shared__ unsigned short csrS[EPG];                                // 6400 B
  __shared__ int offsS[NKEY + 1];                                     // 6404 B
  __shared__ float msgS[F_ + 1];                                      // 516 B  -> 154888 B

  int g = blockIdx.x, tid = threadIdx.x;
  int lane = tid & 63, wave = tid >> 6;
  int m32 = lane & 31, kh = lane >> 5;

  // ---- setup scratch aliased inside hbuf1 (dead until first odd-B commit) ----
  int*   Sint = (int*)hbuf1;
  int*   cnt  = Sint;                    // [1600]
  int*   cur  = Sint + 1600;             // [1600]
  int*   eRec = Sint + 3200;             // [3200]
  float* comb = (float*)(Sint + 6400);   // [256]
  float* red  = (float*)(Sint + 6656);   // [128]   => 27136 B < 54400 B

  // ---- issue (l=0, r=0) B-fragment loads immediately (land during phase 0) ----
  f16x8 st0[4];
#pragma unroll
  for (int i = 0; i < 4; i++)
    st0[i] = *((const f16x8*)(wf + i * 4096 + tid * 8));

  // ---- phase 0: stage x -> hbuf0 (f16); zero cnt/cur; msg combined features ----
  for (int i = tid; i < P_ * 32; i += 512) {
    int row = i >> 5, c4 = i & 31;
    const float4 v = ((const float4*)x)[(g * P_ + row) * 32 + c4];
    f16x4 pk = { (_Float16)v.x, (_Float16)v.y, (_Float16)v.z, (_Float16)v.w };
    *((f16x4*)&hbuf0[row * HROW + c4 * 4]) = pk;
  }
  for (int i = tid; i < NKEY; i += 512) { cnt[i] = 0; cur[i] = 0; }
  if (tid < F_) {
    int tok = (int)message[g * 2];
    float cont = message[g * 2 + 1];
    comb[tid] = embed[tok * F_ + tid];
    float ce = cont * cw[tid] + cb[tid];
    comb[F_ + tid] = ce > 0.0f ? ce : 0.0f;
  }
#pragma unroll
  for (int i = 0; i < 4; i++)
    *((f16x8*)(Bstage + i * 4096 + tid * 8)) = st0[i];
  __syncthreads();

  // ---- phase 1 (wave-specialized): edge ingest || message matmul ----
  int base = g * EPG, nbase = g * P_;
  if (wave < 6) {
    for (int e = wave * 64 + lane; e < EPG; e += 384) {
      int s = ei[base + e] - nbase;
      int d = ei[E_ + base + e] - nbase;
      int r = et[base + e];
      eRec[e] = s | (d << 8) | (r << 16);
      atomicAdd(&cnt[r * P_ + d], 1);
    }
  } else {
    int col = tid & 127;
    float acc = 0.0f;
#pragma unroll 16
    for (int k2 = 0; k2 < 256; k2++) acc += comb[k2] * mw[k2 * F_ + col];
    red[col] = acc;
  }
  __syncthreads();

  // ---- phase 2: wave0 = offset scan (shfl); wave1 = msg finalize ----
  if (wave == 0) {
    int4 vv[8];
    int osum = 0;
    if (lane < 50) {
      const int4* cp = (const int4*)(cnt + lane * 32);
#pragma unroll
      for (int i = 0; i < 8; i++) { vv[i] = cp[i]; osum += vv[i].x + vv[i].y + vv[i].z + vv[i].w; }
    }
    int incl = osum;
#pragma unroll
    for (int d = 1; d < 64; d <<= 1) {
      int t2 = __shfl_up(incl, d, 64);
      if (lane >= d) incl += t2;
    }
    int run = incl - osum;   // exclusive prefix
    if (lane < 50) {
#pragma unroll
      for (int i = 0; i < 8; i++) {
        offsS[lane * 32 + i * 4 + 0] = run; run += vv[i].x;
        offsS[lane * 32 + i * 4 + 1] = run; run += vv[i].y;
        offsS[lane * 32 + i * 4 + 2] = run; run += vv[i].z;
        offsS[lane * 32 + i * 4 + 3] = run; run += vv[i].w;
      }
    }
    if (lane == 0) offsS[NKEY] = EPG;
  } else if (wave == 1) {
    float m0 = mb[lane] + red[lane];
    float m1 = mb[lane + 64] + red[lane + 64];
    m0 = m0 > 0.0f ? m0 : 0.0f;
    m1 = m1 > 0.0f ? m1 : 0.0f;
    msgS[lane] = m0; msgS[lane + 64] = m1;
    float p = m0 * b2[lane] + m1 * b2[lane + 64];
#pragma unroll
    for (int d = 32; d > 0; d >>= 1) p += __shfl_xor(p, d, 64);
    if (lane == 0) msgS[F_] = p;
  }
  __syncthreads();

  // ---- phase 3: CSR scatter from LDS records ----
  for (int e = tid; e < EPG; e += 512) {
    int rec = eRec[e];
    int s = rec & 255, d = (rec >> 8) & 255, r = rec >> 16;
    int key = r * P_ + d;
    int pos = atomicAdd(&cur[key], 1);
    csrS[offsS[key] + pos] = (unsigned short)s;
  }
  __syncthreads();   // hbuf0 + csr + offs + msg + Bstage(l0,r0) ready; hbuf1 scratch dead

  // ---- fused layers: wave w owns rows [w*25, w*25+25); pipelined r-loop ----
  int jobBase = wave * 25;
  bool rowAct = (m32 < 25);
  int myD = jobBase + m32;
  int ck = kh * 8;
  int rowA = jobBase + (rowAct ? m32 : 24);

  for (int l = 0; l < 2; l++) {
    const _Float16* Ap = (l == 0) ? hbuf0 : hbuf1;
    _Float16* balt = (l == 0) ? hbuf1 : hbuf0;   // odd-r B buffer aliases the dead hbuf
    f32x16 acc[4];
#pragma unroll
    for (int nt = 0; nt < 4; nt++)
#pragma unroll
      for (int i = 0; i < 16; i++) acc[nt][i] = 0.0f;
    const _Float16* wl = wf + l * (9 * BSTG);

    f16x8 aA[8], aB[8];
    gather_rel(aA, Ap, csrS, offsS, 0 * P_ + myD, rowAct, ck);   // prologue: r=0

    for (int p = 0; p < 4; p++) {
      int r1 = 2 * p + 1;
      // -- even half: MFMA(2p) from Bstage; stage B(2p+1)->balt; gather(2p+1)->aB --
      f16x8 st2[4];
      {
        const _Float16* wn = wl + r1 * BSTG;
#pragma unroll
        for (int i = 0; i < 4; i++)
          st2[i] = *((const f16x8*)(wn + i * 4096 + tid * 8));
      }
      mfma_rel(acc, aA, Bstage, lane);
      gather_rel(aB, Ap, csrS, offsS, r1 * P_ + myD, rowAct, ck);
#pragma unroll
      for (int i = 0; i < 4; i++)
        *((f16x8*)(balt + i * 4096 + tid * 8)) = st2[i];
      __syncthreads();
      // -- odd half: MFMA(2p+1) from balt; stage B(2p+2)->Bstage; gather(2p+2)->aA --
      {
        const _Float16* wn = wl + (r1 + 1) * BSTG;
#pragma unroll
        for (int i = 0; i < 4; i++)
          st2[i] = *((const f16x8*)(wn + i * 4096 + tid * 8));
      }
      mfma_rel(acc, aB, balt, lane);
      if (p < 3)
        gather_rel(aA, Ap, csrS, offsS, (2 * p + 2) * P_ + myD, rowAct, ck);
      else
        gather_root(aA, Ap, rowA, ck);   // pipeline slot for r=8 (root)
#pragma unroll
      for (int i = 0; i < 4; i++)
        *((f16x8*)(Bstage + i * 4096 + tid * 8)) = st2[i];
      __syncthreads();
    }
    // -- final r=8 (root): B(8) resident in Bstage --
    if (l == 0) {
      f16x8 st3[4];
      const _Float16* wn = wf + 9 * BSTG;   // (l=1, r=0)
#pragma unroll
      for (int i = 0; i < 4; i++)
        st3[i] = *((const f16x8*)(wn + i * 4096 + tid * 8));
      mfma_rel(acc, aA, Bstage, lane);
      __syncthreads();   // all waves done reading Bstage(8) and all l=0 gathers of hbuf0/hbuf1-B
#pragma unroll
      for (int i = 0; i < 4; i++)
        *((f16x8*)(Bstage + i * 4096 + tid * 8)) = st3[i];   // visible after epilogue barrier
      // epilogue: h' = relu(acc + b1) -> hbuf1
#pragma unroll
      for (int nt = 0; nt < 4; nt++) {
        int col = nt * 32 + m32;
        float bias = b1[col];
#pragma unroll
        for (int reg = 0; reg < 16; reg++) {
          int row = (reg & 3) + 8 * (reg >> 2) + 4 * kh;
          if (row < 25) {
            float v = acc[nt][reg] + bias;
            v = v > 0.0f ? v : 0.0f;
            hbuf1[(jobBase + row) * HROW + col] = (_Float16)v;
          }
        }
      }
      __syncthreads();   // h' + Bstage(l1,r0) complete before layer-2 gathers/MFMA
    } else {
      mfma_rel(acc, aA, Bstage, lane);
      // score = dot(node_emb, msg) + dot(b2, msg)
      float db2 = msgS[F_];
#pragma unroll
      for (int reg = 0; reg < 16; reg++) {
        int row = (reg & 3) + 8 * (reg >> 2) + 4 * kh;
        float p = 0.0f;
#pragma unroll
        for (int nt = 0; nt < 4; nt++)
          p += acc[nt][reg] * msgS[nt * 32 + m32];
        p += __shfl_xor(p, 16, 32);
        p += __shfl_xor(p, 8, 32);
        p += __shfl_xor(p, 4, 32);
        p += __shfl_xor(p, 2, 32);
        p += __shfl_xor(p, 1, 32);
        if (m32 == 0 && row < 25)
          out[g * P_ + jobBase + row] = p + db2;
      }
    }
  }
}

extern "C" void kernel_launch(void* const* d_in, const int* in_sizes, int n_in,
                              void* d_out, int out_size, void* d_ws, size_t ws_size,
                              hipStream_t stream) {
  const float* message = (const float*)d_in[0];
  const float* x       = (const float*)d_in[1];
  const int*   ei      = (const int*)d_in[2];
  const int*   et      = (const int*)d_in[3];
  const float* W1      = (const float*)d_in[6];
  const float* root1   = (const float*)d_in[7];
  const float* b1      = (const float*)d_in[8];
  const float* W2      = (const float*)d_in[9];
  const float* root2   = (const float*)d_in[10];
  const float* b2      = (const float*)d_in[11];
  const float* embed   = (const float*)d_in[12];
  const float* cw      = (const float*)d_in[13];
  const float* cb      = (const float*)d_in[14];
  const float* mw      = (const float*)d_in[15];
  const float* mb      = (const float*)d_in[16];

  _Float16* wfrag = (_Float16*)d_ws;   // 589,824 B
  float*    out   = (float*)d_out;

  hipLaunchKernelGGL(k_wstage, dim3(1152), dim3(256), 0, stream, W1, root1, W2, root2, wfrag);
  hipLaunchKernelGGL(k_main, dim3(G_), dim3(512), 0, stream, x, ei, et, wfrag, b1, b2,
                     message, embed, cw, cb, mw, mb, out);
}